// Round 1
// baseline (944.570 us; speedup 1.0000x reference)
//
#include <hip/hip_runtime.h>
#include <math.h>

#define N1c 10000
#define N2c 10000
#define F_INc 256
#define Ec 480000
#define Pc 200000
#define HIDc 128
#define Hc 8
#define DHc 16
#define Lc 2

__device__ __forceinline__ float gelu_f(float x) {
    const float k0 = 0.7978845608028654f;
    const float k1 = 0.044715f;
    float x3 = x * x * x;
    float t = tanhf(k0 * (x + k1 * x3));
    return 0.5f * x * (1.0f + t);
}

// ---------------- effective weights: Wk_eff = Wk @ blockdiag(arel)*prior/4 ; Wv_eff = Wv @ blockdiag(mrel)
// mi in [0,8): l=mi>>2, t=(mi>>1)&1, which=mi&1 (0=K-side w/ prior scale, 1=V-side)
__global__ __launch_bounds__(256) void make_eff_kernel(
    const float* __restrict__ Wk, const float* __restrict__ bk,
    const float* __restrict__ Wv, const float* __restrict__ bv,
    const float* __restrict__ arel, const float* __restrict__ mrel,
    const float* __restrict__ prior,
    float* __restrict__ WeffK, float* __restrict__ beffK,
    float* __restrict__ WeffV, float* __restrict__ beffV)
{
    int gid = blockIdx.x * 256 + threadIdx.x;   // 8 * 16384 threads
    int mi = gid >> 14;
    int idx = gid & 16383;
    int lt = mi >> 1;          // l*2+t in [0,4)
    int which = mi & 1;
    int c = idx >> 7;          // 0..127 (input channel)
    int he = idx & 127;        // h*16+e
    int h = he >> 4, e = he & 15;
    const float* W = (which == 0 ? Wk : Wv) + lt * 128 * 128;
    const float* b = (which == 0 ? bk : bv) + lt * 128;
    const float* R = (which == 0 ? arel : mrel) + lt * Hc * DHc * DHc;
    float sc = (which == 0) ? prior[lt * Hc + h] * 0.25f : 1.0f;
    float acc = 0.f;
    #pragma unroll
    for (int d = 0; d < 16; d++)
        acc += W[c * 128 + h * 16 + d] * R[(h * 16 + d) * 16 + e];
    float* Weff = (which == 0 ? WeffK : WeffV) + lt * 128 * 128;
    Weff[c * 128 + he] = acc * sc;
    if (c == 0) {
        float bacc = 0.f;
        #pragma unroll
        for (int d = 0; d < 16; d++)
            bacc += b[h * 16 + d] * R[(h * 16 + d) * 16 + e];
        float* beff = (which == 0 ? beffK : beffV) + lt * 128;
        beff[he] = bacc * sc;
    }
}

// ---------------- CSR build ----------------
__global__ __launch_bounds__(256) void hist_kernel(const int* __restrict__ dst, int* __restrict__ deg, int nE) {
    int e = blockIdx.x * 256 + threadIdx.x;
    if (e < nE) atomicAdd(&deg[dst[e]], 1);
}

__global__ __launch_bounds__(1024) void scan_kernel(const int* __restrict__ deg, int* __restrict__ rowptr, int n) {
    __shared__ int sums[1024];
    int t = threadIdx.x;
    const int CH = (n + 1023) / 1024;   // 10 for n=10000
    int base = t * CH;
    int loc[16];
    int s = 0;
    for (int j = 0; j < CH; j++) {
        int v = (base + j < n) ? deg[base + j] : 0;
        loc[j] = s; s += v;
    }
    sums[t] = s;
    __syncthreads();
    for (int off = 1; off < 1024; off <<= 1) {
        int v = (t >= off) ? sums[t - off] : 0;
        __syncthreads();
        sums[t] += v;
        __syncthreads();
    }
    int excl = (t == 0) ? 0 : sums[t - 1];
    for (int j = 0; j < CH; j++)
        if (base + j < n) rowptr[base + j] = excl + loc[j];
    if (t == 1023) rowptr[n] = sums[1023];
}

__global__ __launch_bounds__(256) void scatter_kernel(
    const int* __restrict__ src, const int* __restrict__ dst,
    const int* __restrict__ rowptr, int* __restrict__ fill,
    int* __restrict__ esrc, int nE)
{
    int e = blockIdx.x * 256 + threadIdx.x;
    if (e < nE) {
        int d = dst[e];
        int pos = rowptr[d] + atomicAdd(&fill[d], 1);
        esrc[pos] = src[e];
    }
}

// ---------------- generic fp32 GEMM, N fixed 128, 64x64 tile, 4x4 microtile ----------------
// A[M,K] (ldA), W[K,128], bias[128]; optional gelu on A-load, relu on out,
// skip-blend: C = sig*val + (1-sig)*Hold
template<int A_GELU, int OUT_RELU, int SKIP>
__global__ __launch_bounds__(256) void gemm_kernel(
    const float* __restrict__ A, int ldA,
    const float* __restrict__ W,
    const float* __restrict__ bias,
    float* __restrict__ C, int ldC,
    int M, int K,
    const float* __restrict__ skipv,
    const float* __restrict__ Hold, int ldH)
{
    __shared__ float As[32][68];  // [k][m], padded for b128 alignment + no conflicts
    __shared__ float Ws[32][68];  // [k][n]
    int tid = threadIdx.x;
    int tx = tid & 15, ty = tid >> 4;
    int mBase = blockIdx.x * 64;
    int nBase = blockIdx.y * 64;
    float acc[4][4] = {};
    for (int k0 = 0; k0 < K; k0 += 32) {
        #pragma unroll
        for (int r = 0; r < 8; r++) {
            int li = tid + r * 256;
            int ml = li >> 5, kl = li & 31;
            int row = mBase + ml;
            float v = 0.f;
            if (row < M) v = A[(size_t)row * ldA + k0 + kl];
            if (A_GELU) v = gelu_f(v);
            As[kl][ml] = v;
        }
        #pragma unroll
        for (int r = 0; r < 8; r++) {
            int li = tid + r * 256;
            int kl = li >> 6, nl = li & 63;
            Ws[kl][nl] = W[(size_t)(k0 + kl) * 128 + nBase + nl];
        }
        __syncthreads();
        #pragma unroll
        for (int k = 0; k < 32; k++) {
            float av[4], bv[4];
            #pragma unroll
            for (int i = 0; i < 4; i++) av[i] = As[k][ty * 4 + i];
            #pragma unroll
            for (int j = 0; j < 4; j++) bv[j] = Ws[k][tx * 4 + j];
            #pragma unroll
            for (int i = 0; i < 4; i++)
                #pragma unroll
                for (int j = 0; j < 4; j++)
                    acc[i][j] += av[i] * bv[j];
        }
        __syncthreads();
    }
    float sig = 0.f;
    if (SKIP) sig = 1.f / (1.f + __expf(-skipv[0]));
    #pragma unroll
    for (int i = 0; i < 4; i++) {
        int row = mBase + ty * 4 + i;
        if (row >= M) continue;
        #pragma unroll
        for (int j = 0; j < 4; j++) {
            int col = nBase + tx * 4 + j;
            float v = acc[i][j] + bias[col];
            if (OUT_RELU) v = fmaxf(v, 0.f);
            if (SKIP) v = sig * v + (1.f - sig) * Hold[(size_t)row * ldH + col];
            C[(size_t)row * ldC + col] = v;
        }
    }
}

// ---------------- per-dst-node online softmax attention aggregate ----------------
// block = 128 threads (h = tid>>4, d = tid&15), one block per dst node
__global__ __launch_bounds__(128) void attend_kernel(
    const float* __restrict__ Q,
    const float* __restrict__ Kt,
    const float* __restrict__ Vt,
    const int* __restrict__ rowptr,
    const int* __restrict__ esrc,
    float* __restrict__ Out)
{
    int n = blockIdx.x;
    int tid = threadIdx.x;
    float q = Q[n * 128 + tid];
    int beg = rowptr[n], end = rowptr[n + 1];
    float m = -INFINITY, ssum = 0.f, acc = 0.f;
    for (int i = beg; i < end; i++) {
        int s = esrc[i];
        float kt = Kt[(size_t)s * 128 + tid];
        float vt = Vt[(size_t)s * 128 + tid];
        float part = q * kt;
        part += __shfl_xor(part, 1, 16);
        part += __shfl_xor(part, 2, 16);
        part += __shfl_xor(part, 4, 16);
        part += __shfl_xor(part, 8, 16);
        float nm = fmaxf(m, part);
        float alpha = __expf(m - nm);    // first iter: exp(-inf)=0
        float p = __expf(part - nm);
        ssum = ssum * alpha + p;
        acc = acc * alpha + p * vt;
        m = nm;
    }
    Out[n * 128 + tid] = acc / (ssum + 1e-16f);
}

// ---------------- final gathered dot products ----------------
__global__ __launch_bounds__(256) void pred_kernel(
    const float* __restrict__ Em, const float* __restrict__ Ed,
    const int* __restrict__ eidx, float* __restrict__ out)
{
    int wave = (blockIdx.x * 256 + threadIdx.x) >> 6;
    int lane = threadIdx.x & 63;
    if (wave >= Pc) return;
    int m = eidx[wave];
    int d = eidx[Pc + wave];
    const float4* a = (const float4*)(Em + (size_t)m * 256);
    const float4* b = (const float4*)(Ed + (size_t)d * 256);
    float4 av = a[lane], bv = b[lane];
    float s = av.x * bv.x + av.y * bv.y + av.z * bv.z + av.w * bv.w;
    s += __shfl_xor(s, 1);
    s += __shfl_xor(s, 2);
    s += __shfl_xor(s, 4);
    s += __shfl_xor(s, 8);
    s += __shfl_xor(s, 16);
    s += __shfl_xor(s, 32);
    if (lane == 0) out[wave] = s;
}

extern "C" void kernel_launch(void* const* d_in, const int* in_sizes, int n_in,
                              void* d_out, int out_size, void* d_ws, size_t ws_size,
                              hipStream_t stream)
{
    const float* x1   = (const float*)d_in[0];
    const float* x2   = (const float*)d_in[1];
    const int*   ei12 = (const int*)d_in[2];
    const int*   ei21 = (const int*)d_in[3];
    const int*   eidx = (const int*)d_in[4];
    const float* Win1 = (const float*)d_in[5];
    const float* bin1 = (const float*)d_in[6];
    const float* Win2 = (const float*)d_in[7];
    const float* bin2 = (const float*)d_in[8];
    const float* Wk   = (const float*)d_in[9];
    const float* bk   = (const float*)d_in[10];
    const float* Wq   = (const float*)d_in[11];
    const float* bq   = (const float*)d_in[12];
    const float* Wv   = (const float*)d_in[13];
    const float* bv   = (const float*)d_in[14];
    const float* Wa   = (const float*)d_in[15];
    const float* ba   = (const float*)d_in[16];
    const float* skip = (const float*)d_in[17];
    const float* arel = (const float*)d_in[18];
    const float* mrel = (const float*)d_in[19];
    const float* prior= (const float*)d_in[20];

    char* ws = (char*)d_ws;
    size_t off = 0;
    auto allocF = [&](size_t n) { float* p = (float*)(ws + off); off += n * sizeof(float); return p; };
    auto allocI = [&](size_t n) { int* p = (int*)(ws + off); off += n * sizeof(int); return p; };

    float* h1   = allocF((size_t)N1c * HIDc);
    float* h2   = allocF((size_t)N2c * HIDc);
    float* Q1   = allocF((size_t)N1c * HIDc);
    float* K1   = allocF((size_t)N1c * HIDc);
    float* V1   = allocF((size_t)N1c * HIDc);
    float* Q2   = allocF((size_t)N2c * HIDc);
    float* K2   = allocF((size_t)N2c * HIDc);
    float* V2   = allocF((size_t)N2c * HIDc);
    float* agg1 = allocF((size_t)N1c * HIDc);
    float* agg2 = allocF((size_t)N2c * HIDc);
    float* Em   = allocF((size_t)N1c * 256);
    float* Ed   = allocF((size_t)N2c * 256);
    float* WeffK = allocF(4 * 128 * 128);
    float* beffK = allocF(4 * 128);
    float* WeffV = allocF(4 * 128 * 128);
    float* beffV = allocF(4 * 128);
    int* deg12 = allocI(N2c);
    int* deg21 = allocI(N1c);
    int* rp12  = allocI(N2c + 1);
    int* rp21  = allocI(N1c + 1);
    int* fill12 = allocI(N2c);
    int* fill21 = allocI(N1c);
    int* es12  = allocI(Ec);
    int* es21  = allocI(Ec);

    hipMemsetAsync(deg12, 0, N2c * sizeof(int), stream);
    hipMemsetAsync(deg21, 0, N1c * sizeof(int), stream);
    hipMemsetAsync(fill12, 0, N2c * sizeof(int), stream);
    hipMemsetAsync(fill21, 0, N1c * sizeof(int), stream);

    make_eff_kernel<<<512, 256, 0, stream>>>(Wk, bk, Wv, bv, arel, mrel, prior,
                                             WeffK, beffK, WeffV, beffV);

    const int EB = (Ec + 255) / 256;
    hist_kernel<<<EB, 256, 0, stream>>>(ei12 + Ec, deg12, Ec);   // dst = ei12[1] (N2)
    hist_kernel<<<EB, 256, 0, stream>>>(ei21 + Ec, deg21, Ec);   // dst = ei21[1] (N1)
    scan_kernel<<<1, 1024, 0, stream>>>(deg12, rp12, N2c);
    scan_kernel<<<1, 1024, 0, stream>>>(deg21, rp21, N1c);
    scatter_kernel<<<EB, 256, 0, stream>>>(ei12, ei12 + Ec, rp12, fill12, es12, Ec);
    scatter_kernel<<<EB, 256, 0, stream>>>(ei21, ei21 + Ec, rp21, fill21, es21, Ec);

    dim3 gg((N1c + 63) / 64, 2);
    // input projections with relu
    gemm_kernel<0, 1, 0><<<gg, 256, 0, stream>>>(x1, F_INc, Win1, bin1, h1, 128, N1c, F_INc, nullptr, nullptr, 0);
    gemm_kernel<0, 1, 0><<<gg, 256, 0, stream>>>(x2, F_INc, Win2, bin2, h2, 128, N2c, F_INc, nullptr, nullptr, 0);

    for (int l = 0; l < Lc; l++) {
        const float* A1 = (l == 0) ? h1 : Em;  int ld1 = (l == 0) ? 128 : 256;
        const float* A2 = (l == 0) ? h2 : Ed;  int ld2 = (l == 0) ? 128 : 256;
        int lt0 = l * 2 + 0, lt1 = l * 2 + 1;
        // node set 1 projections (t=0 weights)
        gemm_kernel<0, 0, 0><<<gg, 256, 0, stream>>>(A1, ld1, Wq + lt0 * 16384, bq + lt0 * 128, Q1, 128, N1c, 128, nullptr, nullptr, 0);
        gemm_kernel<0, 0, 0><<<gg, 256, 0, stream>>>(A1, ld1, WeffK + lt0 * 16384, beffK + lt0 * 128, K1, 128, N1c, 128, nullptr, nullptr, 0);
        gemm_kernel<0, 0, 0><<<gg, 256, 0, stream>>>(A1, ld1, WeffV + lt0 * 16384, beffV + lt0 * 128, V1, 128, N1c, 128, nullptr, nullptr, 0);
        // node set 2 projections (t=1 weights)
        gemm_kernel<0, 0, 0><<<gg, 256, 0, stream>>>(A2, ld2, Wq + lt1 * 16384, bq + lt1 * 128, Q2, 128, N2c, 128, nullptr, nullptr, 0);
        gemm_kernel<0, 0, 0><<<gg, 256, 0, stream>>>(A2, ld2, WeffK + lt1 * 16384, beffK + lt1 * 128, K2, 128, N2c, 128, nullptr, nullptr, 0);
        gemm_kernel<0, 0, 0><<<gg, 256, 0, stream>>>(A2, ld2, WeffV + lt1 * 16384, beffV + lt1 * 128, V2, 128, N2c, 128, nullptr, nullptr, 0);
        // attend: n1 -> n2 (dst=n2, uses type-0 k/v from node set 1, q from node set 2)
        attend_kernel<<<N2c, 128, 0, stream>>>(Q2, K1, V1, rp12, es12, agg2);
        // attend: n2 -> n1
        attend_kernel<<<N1c, 128, 0, stream>>>(Q1, K2, V2, rp21, es21, agg1);
        // output GEMMs: gelu on A, skip-blend, write into concat buffers
        gemm_kernel<1, 0, 1><<<gg, 256, 0, stream>>>(agg1, 128, Wa + lt0 * 16384, ba + lt0 * 128,
                                                     Em + l * 128, 256, N1c, 128,
                                                     skip + lt0, A1, ld1);
        gemm_kernel<1, 0, 1><<<gg, 256, 0, stream>>>(agg2, 128, Wa + lt1 * 16384, ba + lt1 * 128,
                                                     Ed + l * 128, 256, N2c, 128,
                                                     skip + lt1, A2, ld2);
    }

    pred_kernel<<<(Pc * 64 + 255) / 256, 256, 0, stream>>>(Em, Ed, eidx, (float*)d_out);
}

// Round 2
// 622.068 us; speedup vs baseline: 1.5184x; 1.5184x over previous
//
#include <hip/hip_runtime.h>
#include <math.h>

#define N1c 10000
#define N2c 10000
#define F_INc 256
#define Ec 480000
#define Pc 200000
#define HIDc 128
#define Hc 8
#define DHc 16
#define Lc 2

__device__ __forceinline__ float gelu_f(float x) {
    const float k0 = 0.7978845608028654f;
    const float k1 = 0.044715f;
    float x3 = x * x * x;
    float t = tanhf(k0 * (x + k1 * x3));
    return 0.5f * x * (1.0f + t);
}

// ---------------- combined effective weights ----------------
// Wqkv[lt][c][col], col<128: Wq; 128..255: Wk@arel*prior/4; 256..383: Wv@mrel
__global__ __launch_bounds__(128) void make_eff_kernel(
    const float* __restrict__ Wq, const float* __restrict__ bq,
    const float* __restrict__ Wk, const float* __restrict__ bk,
    const float* __restrict__ Wv, const float* __restrict__ bv,
    const float* __restrict__ arel, const float* __restrict__ mrel,
    const float* __restrict__ prior,
    float* __restrict__ Wqkv, float* __restrict__ bqkv)
{
    int col = blockIdx.x * 128 + threadIdx.x;   // 0..383
    int c = blockIdx.y;                          // 0..127
    int lt = blockIdx.z;                         // 0..3
    float* Wout = Wqkv + (size_t)lt * 128 * 384;
    float* bout = bqkv + lt * 384;
    if (col < 128) {
        Wout[c * 384 + col] = Wq[lt * 16384 + c * 128 + col];
        if (c == 0) bout[col] = bq[lt * 128 + col];
        return;
    }
    int which = (col < 256) ? 0 : 1;
    int he = col - (which ? 256 : 128);
    int h = he >> 4, e = he & 15;
    const float* W = (which == 0 ? Wk : Wv) + lt * 16384;
    const float* b = (which == 0 ? bk : bv) + lt * 128;
    const float* R = (which == 0 ? arel : mrel) + lt * 2048;
    float sc = (which == 0) ? prior[lt * 8 + h] * 0.25f : 1.0f;
    float acc = 0.f;
    #pragma unroll
    for (int d = 0; d < 16; d++)
        acc += W[c * 128 + h * 16 + d] * R[(h * 16 + d) * 16 + e];
    Wout[c * 384 + col] = acc * sc;
    if (c == 0) {
        float bacc = 0.f;
        #pragma unroll
        for (int d = 0; d < 16; d++)
            bacc += b[h * 16 + d] * R[(h * 16 + d) * 16 + e];
        bout[col] = bacc * sc;
    }
}

// ---------------- CSR build (both graphs in one dispatch) ----------------
__global__ __launch_bounds__(256) void hist2_kernel(
    const int* __restrict__ d12, const int* __restrict__ d21,
    int* __restrict__ deg12, int* __restrict__ deg21, int nE)
{
    int e = blockIdx.x * 256 + threadIdx.x;
    if (e >= nE) return;
    if (blockIdx.y == 0) atomicAdd(&deg12[d12[e]], 1);
    else                 atomicAdd(&deg21[d21[e]], 1);
}

__global__ __launch_bounds__(1024) void scan2_kernel(
    const int* __restrict__ deg12, int* __restrict__ rp12,
    const int* __restrict__ deg21, int* __restrict__ rp21, int n)
{
    const int* deg = blockIdx.x ? deg21 : deg12;
    int* rowptr = blockIdx.x ? rp21 : rp12;
    __shared__ int sums[1024];
    int t = threadIdx.x;
    const int CH = (n + 1023) / 1024;
    int base = t * CH;
    int loc[16];
    int s = 0;
    for (int j = 0; j < CH; j++) {
        int v = (base + j < n) ? deg[base + j] : 0;
        loc[j] = s; s += v;
    }
    sums[t] = s;
    __syncthreads();
    for (int off = 1; off < 1024; off <<= 1) {
        int v = (t >= off) ? sums[t - off] : 0;
        __syncthreads();
        sums[t] += v;
        __syncthreads();
    }
    int excl = (t == 0) ? 0 : sums[t - 1];
    for (int j = 0; j < CH; j++)
        if (base + j < n) rowptr[base + j] = excl + loc[j];
    if (t == 1023) rowptr[n] = sums[1023];
}

__global__ __launch_bounds__(256) void scatter2_kernel(
    const int* __restrict__ ei12, const int* __restrict__ ei21,
    const int* __restrict__ rp12, const int* __restrict__ rp21,
    int* __restrict__ fill12, int* __restrict__ fill21,
    int* __restrict__ es12, int* __restrict__ es21, int nE)
{
    int e = blockIdx.x * 256 + threadIdx.x;
    if (e >= nE) return;
    const int* src = blockIdx.y ? ei21 : ei12;
    const int* dst = (blockIdx.y ? ei21 : ei12) + Ec;
    const int* rowptr = blockIdx.y ? rp21 : rp12;
    int* fill = blockIdx.y ? fill21 : fill12;
    int* esrc = blockIdx.y ? es21 : es12;
    int d = dst[e];
    int pos = rowptr[d] + atomicAdd(&fill[d], 1);
    esrc[pos] = src[e];
}

// ---------------- fp32 GEMM, 64x64 tile, 4x4 microtile, dual param sets via z ----------------
template<int A_GELU, int OUT_RELU, int SKIP>
__global__ __launch_bounds__(256) void gemm2_kernel(
    const float* __restrict__ A0, const float* __restrict__ A1, int ldA,
    const float* __restrict__ W0, const float* __restrict__ W1, int ldW,
    const float* __restrict__ b0, const float* __restrict__ b1,
    float* __restrict__ C0, float* __restrict__ C1, int ldC,
    int M, int K,
    const float* __restrict__ sk0, const float* __restrict__ sk1,
    const float* __restrict__ H0, const float* __restrict__ H1, int ldH)
{
    int z = blockIdx.z;
    const float* A = z ? A1 : A0;
    const float* W = z ? W1 : W0;
    const float* bias = z ? b1 : b0;
    float* C = z ? C1 : C0;
    const float* skipv = z ? sk1 : sk0;
    const float* Hold = z ? H1 : H0;

    __shared__ float As[32][68];
    __shared__ float Ws[32][68];
    int tid = threadIdx.x;
    int tx = tid & 15, ty = tid >> 4;
    int mBase = blockIdx.x * 64;
    int nBase = blockIdx.y * 64;
    float acc[4][4] = {};
    for (int k0 = 0; k0 < K; k0 += 32) {
        #pragma unroll
        for (int r = 0; r < 8; r++) {
            int li = tid + r * 256;
            int ml = li >> 5, kl = li & 31;
            int row = mBase + ml;
            float v = 0.f;
            if (row < M) v = A[(size_t)row * ldA + k0 + kl];
            if (A_GELU) v = gelu_f(v);
            As[kl][ml] = v;
        }
        #pragma unroll
        for (int r = 0; r < 8; r++) {
            int li = tid + r * 256;
            int kl = li >> 6, nl = li & 63;
            Ws[kl][nl] = W[(size_t)(k0 + kl) * ldW + nBase + nl];
        }
        __syncthreads();
        #pragma unroll
        for (int k = 0; k < 32; k++) {
            float av[4], bv[4];
            #pragma unroll
            for (int i = 0; i < 4; i++) av[i] = As[k][ty * 4 + i];
            #pragma unroll
            for (int j = 0; j < 4; j++) bv[j] = Ws[k][tx * 4 + j];
            #pragma unroll
            for (int i = 0; i < 4; i++)
                #pragma unroll
                for (int j = 0; j < 4; j++)
                    acc[i][j] += av[i] * bv[j];
        }
        __syncthreads();
    }
    float sig = 0.f;
    if (SKIP) sig = 1.f / (1.f + __expf(-skipv[0]));
    #pragma unroll
    for (int i = 0; i < 4; i++) {
        int row = mBase + ty * 4 + i;
        if (row >= M) continue;
        #pragma unroll
        for (int j = 0; j < 4; j++) {
            int col = nBase + tx * 4 + j;
            float v = acc[i][j] + bias[col];
            if (OUT_RELU) v = fmaxf(v, 0.f);
            if (SKIP) v = sig * v + (1.f - sig) * Hold[(size_t)row * ldH + col];
            C[(size_t)row * ldC + col] = v;
        }
    }
}

// ---------------- merged attend: both directions, 4-edge ILP, float2 lanes ----------------
// block = 64 threads, one dst node per block; thread t: elems (2t,2t+1), head t>>3
__device__ __forceinline__ void upd_state(float& m, float& s, float2& a,
                                          float p, float2 v) {
    float nm = fmaxf(m, p);
    float al = __expf(m - nm);
    float pe = __expf(p - nm);
    s = s * al + pe;
    a.x = a.x * al + pe * v.x;
    a.y = a.y * al + pe * v.y;
    m = nm;
}

__global__ __launch_bounds__(64) void attend2_kernel(
    const float* __restrict__ QKV1, const float* __restrict__ QKV2,
    const int* __restrict__ rp12, const int* __restrict__ es12,
    const int* __restrict__ rp21, const int* __restrict__ es21,
    float* __restrict__ agg1, float* __restrict__ agg2)
{
    int b = blockIdx.x;
    int t = threadIdx.x;
    const float* Qb; const float* KV; const int* rp; const int* es; float* out; int n;
    if (b < N2c) { n = b;       Qb = QKV2; KV = QKV1; rp = rp12; es = es12; out = agg2; }
    else         { n = b - N2c; Qb = QKV1; KV = QKV2; rp = rp21; es = es21; out = agg1; }

    float2 q = *(const float2*)(Qb + (size_t)n * 384 + 2 * t);
    int beg = rp[n], end = rp[n + 1];
    float m0 = -INFINITY, m1 = -INFINITY, m2 = -INFINITY, m3 = -INFINITY;
    float s0 = 0.f, s1 = 0.f, s2 = 0.f, s3 = 0.f;
    float2 a0 = {0.f, 0.f}, a1 = {0.f, 0.f}, a2 = {0.f, 0.f}, a3 = {0.f, 0.f};
    int i = beg;
    for (; i + 4 <= end; i += 4) {
        int e0 = es[i], e1 = es[i + 1], e2 = es[i + 2], e3 = es[i + 3];
        const float* r0 = KV + (size_t)e0 * 384 + 2 * t;
        const float* r1 = KV + (size_t)e1 * 384 + 2 * t;
        const float* r2 = KV + (size_t)e2 * 384 + 2 * t;
        const float* r3 = KV + (size_t)e3 * 384 + 2 * t;
        float2 k0 = *(const float2*)(r0 + 128), v0 = *(const float2*)(r0 + 256);
        float2 k1 = *(const float2*)(r1 + 128), v1 = *(const float2*)(r1 + 256);
        float2 k2 = *(const float2*)(r2 + 128), v2 = *(const float2*)(r2 + 256);
        float2 k3 = *(const float2*)(r3 + 128), v3 = *(const float2*)(r3 + 256);
        float p0 = q.x * k0.x + q.y * k0.y;
        float p1 = q.x * k1.x + q.y * k1.y;
        float p2 = q.x * k2.x + q.y * k2.y;
        float p3 = q.x * k3.x + q.y * k3.y;
        p0 += __shfl_xor(p0, 1, 8); p1 += __shfl_xor(p1, 1, 8);
        p2 += __shfl_xor(p2, 1, 8); p3 += __shfl_xor(p3, 1, 8);
        p0 += __shfl_xor(p0, 2, 8); p1 += __shfl_xor(p1, 2, 8);
        p2 += __shfl_xor(p2, 2, 8); p3 += __shfl_xor(p3, 2, 8);
        p0 += __shfl_xor(p0, 4, 8); p1 += __shfl_xor(p1, 4, 8);
        p2 += __shfl_xor(p2, 4, 8); p3 += __shfl_xor(p3, 4, 8);
        upd_state(m0, s0, a0, p0, v0);
        upd_state(m1, s1, a1, p1, v1);
        upd_state(m2, s2, a2, p2, v2);
        upd_state(m3, s3, a3, p3, v3);
    }
    for (; i < end; i++) {
        int e0 = es[i];
        const float* r0 = KV + (size_t)e0 * 384 + 2 * t;
        float2 k0 = *(const float2*)(r0 + 128), v0 = *(const float2*)(r0 + 256);
        float p0 = q.x * k0.x + q.y * k0.y;
        p0 += __shfl_xor(p0, 1, 8);
        p0 += __shfl_xor(p0, 2, 8);
        p0 += __shfl_xor(p0, 4, 8);
        upd_state(m0, s0, a0, p0, v0);
    }
    float M = fmaxf(fmaxf(m0, m1), fmaxf(m2, m3));
    float2 o = {0.f, 0.f};
    if (M != -INFINITY) {
        float w0 = __expf(m0 - M), w1 = __expf(m1 - M);
        float w2 = __expf(m2 - M), w3 = __expf(m3 - M);
        float ssum = s0 * w0 + s1 * w1 + s2 * w2 + s3 * w3;
        float inv = 1.f / (ssum + 1e-16f);
        o.x = (a0.x * w0 + a1.x * w1 + a2.x * w2 + a3.x * w3) * inv;
        o.y = (a0.y * w0 + a1.y * w1 + a2.y * w2 + a3.y * w3) * inv;
    }
    *(float2*)(out + (size_t)n * 128 + 2 * t) = o;
}

// ---------------- final gathered dot products ----------------
__global__ __launch_bounds__(256) void pred_kernel(
    const float* __restrict__ Em, const float* __restrict__ Ed,
    const int* __restrict__ eidx, float* __restrict__ out)
{
    int wave = (blockIdx.x * 256 + threadIdx.x) >> 6;
    int lane = threadIdx.x & 63;
    if (wave >= Pc) return;
    int m = eidx[wave];
    int d = eidx[Pc + wave];
    const float4* a = (const float4*)(Em + (size_t)m * 256);
    const float4* b = (const float4*)(Ed + (size_t)d * 256);
    float4 av = a[lane], bv = b[lane];
    float s = av.x * bv.x + av.y * bv.y + av.z * bv.z + av.w * bv.w;
    s += __shfl_xor(s, 1);
    s += __shfl_xor(s, 2);
    s += __shfl_xor(s, 4);
    s += __shfl_xor(s, 8);
    s += __shfl_xor(s, 16);
    s += __shfl_xor(s, 32);
    if (lane == 0) out[wave] = s;
}

extern "C" void kernel_launch(void* const* d_in, const int* in_sizes, int n_in,
                              void* d_out, int out_size, void* d_ws, size_t ws_size,
                              hipStream_t stream)
{
    const float* x1   = (const float*)d_in[0];
    const float* x2   = (const float*)d_in[1];
    const int*   ei12 = (const int*)d_in[2];
    const int*   ei21 = (const int*)d_in[3];
    const int*   eidx = (const int*)d_in[4];
    const float* Win1 = (const float*)d_in[5];
    const float* bin1 = (const float*)d_in[6];
    const float* Win2 = (const float*)d_in[7];
    const float* bin2 = (const float*)d_in[8];
    const float* Wk   = (const float*)d_in[9];
    const float* bk   = (const float*)d_in[10];
    const float* Wq   = (const float*)d_in[11];
    const float* bq   = (const float*)d_in[12];
    const float* Wv   = (const float*)d_in[13];
    const float* bv   = (const float*)d_in[14];
    const float* Wa   = (const float*)d_in[15];
    const float* ba   = (const float*)d_in[16];
    const float* skip = (const float*)d_in[17];
    const float* arel = (const float*)d_in[18];
    const float* mrel = (const float*)d_in[19];
    const float* prior= (const float*)d_in[20];

    char* ws = (char*)d_ws;
    size_t off = 0;
    auto allocF = [&](size_t n) { float* p = (float*)(ws + off); off += n * sizeof(float); return p; };
    auto allocI = [&](size_t n) { int* p = (int*)(ws + off); off += n * sizeof(int); return p; };

    float* h1    = allocF((size_t)N1c * 128);
    float* h2    = allocF((size_t)N2c * 128);
    float* QKV1  = allocF((size_t)N1c * 384);
    float* QKV2  = allocF((size_t)N2c * 384);
    float* agg1  = allocF((size_t)N1c * 128);
    float* agg2  = allocF((size_t)N2c * 128);
    float* Em    = allocF((size_t)N1c * 256);
    float* Ed    = allocF((size_t)N2c * 256);
    float* Wqkv  = allocF(4 * 128 * 384);
    float* bqkv  = allocF(4 * 384);
    int* deg12 = allocI(N2c);      // contiguous block: deg12,deg21,fill12,fill21
    int* deg21 = allocI(N1c);
    int* fill12 = allocI(N2c);
    int* fill21 = allocI(N1c);
    int* rp12  = allocI(N2c + 1);
    int* rp21  = allocI(N1c + 1);
    int* es12  = allocI(Ec);
    int* es21  = allocI(Ec);

    hipMemsetAsync(deg12, 0, (size_t)(N1c + N2c) * 2 * sizeof(int), stream);

    make_eff_kernel<<<dim3(3, 128, 4), 128, 0, stream>>>(
        Wq, bq, Wk, bk, Wv, bv, arel, mrel, prior, Wqkv, bqkv);

    const int EB = (Ec + 255) / 256;
    hist2_kernel<<<dim3(EB, 2), 256, 0, stream>>>(ei12 + Ec, ei21 + Ec, deg12, deg21, Ec);
    scan2_kernel<<<2, 1024, 0, stream>>>(deg12, rp12, deg21, rp21, N1c);
    scatter2_kernel<<<dim3(EB, 2), 256, 0, stream>>>(ei12, ei21, rp12, rp21,
                                                     fill12, fill21, es12, es21, Ec);

    const int MB = (N1c + 63) / 64;   // 157
    // input projections (relu), both node sets in one dispatch
    gemm2_kernel<0, 1, 0><<<dim3(MB, 2, 2), 256, 0, stream>>>(
        x1, x2, F_INc, Win1, Win2, 128, bin1, bin2, h1, h2, 128,
        N1c, F_INc, nullptr, nullptr, nullptr, nullptr, 0);

    for (int l = 0; l < Lc; l++) {
        const float* A1 = (l == 0) ? h1 : Em;  int ld1 = (l == 0) ? 128 : 256;
        const float* A2 = (l == 0) ? h2 : Ed;  int ld2 = (l == 0) ? 128 : 256;
        int lt0 = l * 2 + 0, lt1 = l * 2 + 1;
        // fused QKV projections for both node sets
        gemm2_kernel<0, 0, 0><<<dim3(MB, 6, 2), 256, 0, stream>>>(
            A1, A2, ld1,                       // note: ld1==ld2 always
            Wqkv + (size_t)lt0 * 49152, Wqkv + (size_t)lt1 * 49152, 384,
            bqkv + lt0 * 384, bqkv + lt1 * 384,
            QKV1, QKV2, 384, N1c, 128,
            nullptr, nullptr, nullptr, nullptr, 0);
        // both attends in one dispatch
        attend2_kernel<<<N1c + N2c, 64, 0, stream>>>(
            QKV1, QKV2, rp12, es12, rp21, es21, agg1, agg2);
        // output GEMMs (gelu on A, skip blend) into concat buffers
        gemm2_kernel<1, 0, 1><<<dim3(MB, 2, 2), 256, 0, stream>>>(
            agg1, agg2, 128,
            Wa + (size_t)lt0 * 16384, Wa + (size_t)lt1 * 16384, 128,
            ba + lt0 * 128, ba + lt1 * 128,
            Em + l * 128, Ed + l * 128, 256,
            N1c, 128,
            skip + lt0, skip + lt1,
            A1, A2, ld1);
    }

    pred_kernel<<<(Pc * 64 + 255) / 256, 256, 0, stream>>>(Em, Ed, eidx, (float*)d_out);
}

// Round 3
// 543.417 us; speedup vs baseline: 1.7382x; 1.1447x over previous
//
#include <hip/hip_runtime.h>
#include <math.h>

#define N1c 10000
#define N2c 10000
#define F_INc 256
#define Ec 480000
#define Pc 200000
#define HIDc 128
#define Hc 8
#define DHc 16
#define Lc 2

__device__ __forceinline__ float gelu_f(float x) {
    const float k0 = 0.7978845608028654f;
    const float k1 = 0.044715f;
    float x3 = x * x * x;
    float t = tanhf(k0 * (x + k1 * x3));
    return 0.5f * x * (1.0f + t);
}

__device__ __forceinline__ float bf2f(unsigned short x) {
    union { unsigned int u; float f; } c;
    c.u = ((unsigned int)x) << 16;
    return c.f;
}
__device__ __forceinline__ unsigned short f2bf(float f) {
    union { float f; unsigned int u; } c;
    c.f = f;
    unsigned int u = c.u;
    unsigned int r = (u + 0x7FFFu + ((u >> 16) & 1u)) >> 16;
    return (unsigned short)r;
}

// ---------------- combined effective weights ----------------
// Wqkv[lt][c][col], col<128: Wq; 128..255: Wk@arel*prior/4; 256..383: Wv@mrel
__global__ __launch_bounds__(128) void make_eff_kernel(
    const float* __restrict__ Wq, const float* __restrict__ bq,
    const float* __restrict__ Wk, const float* __restrict__ bk,
    const float* __restrict__ Wv, const float* __restrict__ bv,
    const float* __restrict__ arel, const float* __restrict__ mrel,
    const float* __restrict__ prior,
    float* __restrict__ Wqkv, float* __restrict__ bqkv)
{
    int col = blockIdx.x * 128 + threadIdx.x;   // 0..383
    int c = blockIdx.y;                          // 0..127
    int lt = blockIdx.z;                         // 0..3
    float* Wout = Wqkv + (size_t)lt * 128 * 384;
    float* bout = bqkv + lt * 384;
    if (col < 128) {
        Wout[c * 384 + col] = Wq[lt * 16384 + c * 128 + col];
        if (c == 0) bout[col] = bq[lt * 128 + col];
        return;
    }
    int which = (col < 256) ? 0 : 1;
    int he = col - (which ? 256 : 128);
    int h = he >> 4, e = he & 15;
    const float* W = (which == 0 ? Wk : Wv) + lt * 16384;
    const float* b = (which == 0 ? bk : bv) + lt * 128;
    const float* R = (which == 0 ? arel : mrel) + lt * 2048;
    float sc = (which == 0) ? prior[lt * 8 + h] * 0.25f : 1.0f;
    float acc = 0.f;
    #pragma unroll
    for (int d = 0; d < 16; d++)
        acc += W[c * 128 + h * 16 + d] * R[(h * 16 + d) * 16 + e];
    Wout[c * 384 + col] = acc * sc;
    if (c == 0) {
        float bacc = 0.f;
        #pragma unroll
        for (int d = 0; d < 16; d++)
            bacc += b[h * 16 + d] * R[(h * 16 + d) * 16 + e];
        bout[col] = bacc * sc;
    }
}

// ---------------- CSR build: 2 edge graphs + pair grouping, one dispatch each ----------------
__global__ __launch_bounds__(256) void hist3_kernel(
    const int* __restrict__ ei12, const int* __restrict__ ei21,
    const int* __restrict__ eidx,
    int* __restrict__ deg12, int* __restrict__ deg21, int* __restrict__ degm)
{
    int e = blockIdx.x * 256 + threadIdx.x;
    int z = blockIdx.y;
    if (z == 0)      { if (e < Ec) atomicAdd(&deg12[ei12[Ec + e]], 1); }
    else if (z == 1) { if (e < Ec) atomicAdd(&deg21[ei21[Ec + e]], 1); }
    else             { if (e < Pc) atomicAdd(&degm[eidx[e]], 1); }
}

__global__ __launch_bounds__(1024) void scan3_kernel(
    const int* __restrict__ deg12, int* __restrict__ rp12,
    const int* __restrict__ deg21, int* __restrict__ rp21,
    const int* __restrict__ degm,  int* __restrict__ rpm)
{
    const int n = 10000;
    const int* deg; int* rowptr;
    if (blockIdx.x == 0)      { deg = deg12; rowptr = rp12; }
    else if (blockIdx.x == 1) { deg = deg21; rowptr = rp21; }
    else                      { deg = degm;  rowptr = rpm; }
    __shared__ int sums[1024];
    int t = threadIdx.x;
    const int CH = (n + 1023) / 1024;
    int base = t * CH;
    int loc[16];
    int s = 0;
    for (int j = 0; j < CH; j++) {
        int v = (base + j < n) ? deg[base + j] : 0;
        loc[j] = s; s += v;
    }
    sums[t] = s;
    __syncthreads();
    for (int off = 1; off < 1024; off <<= 1) {
        int v = (t >= off) ? sums[t - off] : 0;
        __syncthreads();
        sums[t] += v;
        __syncthreads();
    }
    int excl = (t == 0) ? 0 : sums[t - 1];
    for (int j = 0; j < CH; j++)
        if (base + j < n) rowptr[base + j] = excl + loc[j];
    if (t == 1023) rowptr[n] = sums[1023];
}

__global__ __launch_bounds__(256) void scatter3_kernel(
    const int* __restrict__ ei12, const int* __restrict__ ei21,
    const int* __restrict__ eidx,
    const int* __restrict__ rp12, const int* __restrict__ rp21, const int* __restrict__ rpm,
    int* __restrict__ fill12, int* __restrict__ fill21, int* __restrict__ fillm,
    int* __restrict__ es12, int* __restrict__ es21, int* __restrict__ ps)
{
    int e = blockIdx.x * 256 + threadIdx.x;
    int z = blockIdx.y;
    if (z == 0) {
        if (e >= Ec) return;
        int d = ei12[Ec + e];
        int pos = rp12[d] + atomicAdd(&fill12[d], 1);
        es12[pos] = ei12[e];
    } else if (z == 1) {
        if (e >= Ec) return;
        int d = ei21[Ec + e];
        int pos = rp21[d] + atomicAdd(&fill21[d], 1);
        es21[pos] = ei21[e];
    } else {
        if (e >= Pc) return;
        int d = eidx[e];
        int pos = rpm[d] + atomicAdd(&fillm[d], 1);
        ps[pos] = e;
    }
}

// ---------------- fp32 GEMM, 64x64 tile, 4x4 microtile, dual param sets via z ----------------
// PACKQKV: cols 0..127 -> fp32 Q (C ptr), cols 128..383 -> bf16 KV[row][256]
template<int A_GELU, int OUT_RELU, int SKIP, int PACKQKV>
__global__ __launch_bounds__(256) void gemm2_kernel(
    const float* __restrict__ A0, const float* __restrict__ A1, int ldA,
    const float* __restrict__ W0, const float* __restrict__ W1, int ldW,
    const float* __restrict__ b0, const float* __restrict__ b1,
    float* __restrict__ C0, float* __restrict__ C1, int ldC,
    unsigned short* __restrict__ KV0, unsigned short* __restrict__ KV1,
    int M, int K,
    const float* __restrict__ sk0, const float* __restrict__ sk1,
    const float* __restrict__ H0, const float* __restrict__ H1, int ldH)
{
    int z = blockIdx.z;
    const float* A = z ? A1 : A0;
    const float* W = z ? W1 : W0;
    const float* bias = z ? b1 : b0;
    float* C = z ? C1 : C0;
    unsigned short* KVo = z ? KV1 : KV0;
    const float* skipv = z ? sk1 : sk0;
    const float* Hold = z ? H1 : H0;

    __shared__ float As[32][68];
    __shared__ float Ws[32][68];
    int tid = threadIdx.x;
    int tx = tid & 15, ty = tid >> 4;
    int mBase = blockIdx.x * 64;
    int nBase = blockIdx.y * 64;
    float acc[4][4] = {};
    for (int k0 = 0; k0 < K; k0 += 32) {
        #pragma unroll
        for (int r = 0; r < 8; r++) {
            int li = tid + r * 256;
            int ml = li >> 5, kl = li & 31;
            int row = mBase + ml;
            float v = 0.f;
            if (row < M) v = A[(size_t)row * ldA + k0 + kl];
            if (A_GELU) v = gelu_f(v);
            As[kl][ml] = v;
        }
        #pragma unroll
        for (int r = 0; r < 8; r++) {
            int li = tid + r * 256;
            int kl = li >> 6, nl = li & 63;
            Ws[kl][nl] = W[(size_t)(k0 + kl) * ldW + nBase + nl];
        }
        __syncthreads();
        #pragma unroll
        for (int k = 0; k < 32; k++) {
            float av[4], bv[4];
            #pragma unroll
            for (int i = 0; i < 4; i++) av[i] = As[k][ty * 4 + i];
            #pragma unroll
            for (int j = 0; j < 4; j++) bv[j] = Ws[k][tx * 4 + j];
            #pragma unroll
            for (int i = 0; i < 4; i++)
                #pragma unroll
                for (int j = 0; j < 4; j++)
                    acc[i][j] += av[i] * bv[j];
        }
        __syncthreads();
    }
    float sig = 0.f;
    if (SKIP) sig = 1.f / (1.f + __expf(-skipv[0]));
    #pragma unroll
    for (int i = 0; i < 4; i++) {
        int row = mBase + ty * 4 + i;
        if (row >= M) continue;
        #pragma unroll
        for (int j = 0; j < 4; j++) {
            int col = nBase + tx * 4 + j;
            float v = acc[i][j] + bias[col];
            if (OUT_RELU) v = fmaxf(v, 0.f);
            if (SKIP) v = sig * v + (1.f - sig) * Hold[(size_t)row * ldH + col];
            if (PACKQKV) {
                if (col < 128) C[(size_t)row * ldC + col] = v;
                else KVo[(size_t)row * 256 + col - 128] = f2bf(v);
            } else {
                C[(size_t)row * ldC + col] = v;
            }
        }
    }
}

// ---------------- merged attend: 2 nodes/block, 32 lanes/node, 4 elems/lane, bf16 KV ----------------
__device__ __forceinline__ void upd4(float& m, float& s, float4& a,
                                     float p, float4 v) {
    float nm = fmaxf(m, p);
    float al = __expf(m - nm);
    float pe = __expf(p - nm);
    s = s * al + pe;
    a.x = a.x * al + pe * v.x;
    a.y = a.y * al + pe * v.y;
    a.z = a.z * al + pe * v.z;
    a.w = a.w * al + pe * v.w;
    m = nm;
}

__device__ __forceinline__ float4 bfv4(ushort4 u) {
    return make_float4(bf2f(u.x), bf2f(u.y), bf2f(u.z), bf2f(u.w));
}

__global__ __launch_bounds__(64) void attend2_kernel(
    const float* __restrict__ Q1, const unsigned short* __restrict__ KV1,
    const float* __restrict__ Q2, const unsigned short* __restrict__ KV2,
    const int* __restrict__ rp12, const int* __restrict__ es12,
    const int* __restrict__ rp21, const int* __restrict__ es21,
    float* __restrict__ agg1, float* __restrict__ agg2)
{
    int b = blockIdx.x;
    int half = threadIdx.x >> 5;
    int l = threadIdx.x & 31;
    const float* Q; const unsigned short* KV; const int* rp; const int* es; float* out; int n;
    if (b < N2c / 2) { n = 2 * b + half;              Q = Q2; KV = KV1; rp = rp12; es = es12; out = agg2; }
    else             { n = 2 * (b - N2c / 2) + half;  Q = Q1; KV = KV2; rp = rp21; es = es21; out = agg1; }

    float4 q = *(const float4*)(Q + (size_t)n * 128 + 4 * l);
    int beg = rp[n], end = rp[n + 1];
    float m0 = -INFINITY, m1 = -INFINITY, m2 = -INFINITY, m3 = -INFINITY;
    float s0 = 0.f, s1 = 0.f, s2 = 0.f, s3 = 0.f;
    float4 a0 = {0,0,0,0}, a1 = {0,0,0,0}, a2 = {0,0,0,0}, a3 = {0,0,0,0};
    int i = beg;
    for (; i + 4 <= end; i += 4) {
        int e0 = es[i], e1 = es[i+1], e2 = es[i+2], e3 = es[i+3];
        const unsigned short* r0 = KV + (size_t)e0 * 256 + 4 * l;
        const unsigned short* r1 = KV + (size_t)e1 * 256 + 4 * l;
        const unsigned short* r2 = KV + (size_t)e2 * 256 + 4 * l;
        const unsigned short* r3 = KV + (size_t)e3 * 256 + 4 * l;
        float4 k0 = bfv4(*(const ushort4*)r0), v0 = bfv4(*(const ushort4*)(r0 + 128));
        float4 k1 = bfv4(*(const ushort4*)r1), v1 = bfv4(*(const ushort4*)(r1 + 128));
        float4 k2 = bfv4(*(const ushort4*)r2), v2 = bfv4(*(const ushort4*)(r2 + 128));
        float4 k3 = bfv4(*(const ushort4*)r3), v3 = bfv4(*(const ushort4*)(r3 + 128));
        float p0 = q.x*k0.x + q.y*k0.y + q.z*k0.z + q.w*k0.w;
        float p1 = q.x*k1.x + q.y*k1.y + q.z*k1.z + q.w*k1.w;
        float p2 = q.x*k2.x + q.y*k2.y + q.z*k2.z + q.w*k2.w;
        float p3 = q.x*k3.x + q.y*k3.y + q.z*k3.z + q.w*k3.w;
        p0 += __shfl_xor(p0, 1, 4); p1 += __shfl_xor(p1, 1, 4);
        p2 += __shfl_xor(p2, 1, 4); p3 += __shfl_xor(p3, 1, 4);
        p0 += __shfl_xor(p0, 2, 4); p1 += __shfl_xor(p1, 2, 4);
        p2 += __shfl_xor(p2, 2, 4); p3 += __shfl_xor(p3, 2, 4);
        upd4(m0, s0, a0, p0, v0);
        upd4(m1, s1, a1, p1, v1);
        upd4(m2, s2, a2, p2, v2);
        upd4(m3, s3, a3, p3, v3);
    }
    for (; i < end; i++) {
        int e0 = es[i];
        const unsigned short* r0 = KV + (size_t)e0 * 256 + 4 * l;
        float4 k0 = bfv4(*(const ushort4*)r0), v0 = bfv4(*(const ushort4*)(r0 + 128));
        float p0 = q.x*k0.x + q.y*k0.y + q.z*k0.z + q.w*k0.w;
        p0 += __shfl_xor(p0, 1, 4);
        p0 += __shfl_xor(p0, 2, 4);
        upd4(m0, s0, a0, p0, v0);
    }
    float M = fmaxf(fmaxf(m0, m1), fmaxf(m2, m3));
    float4 o = {0,0,0,0};
    if (M != -INFINITY) {
        float w0 = __expf(m0 - M), w1 = __expf(m1 - M);
        float w2 = __expf(m2 - M), w3 = __expf(m3 - M);
        float ssum = s0 * w0 + s1 * w1 + s2 * w2 + s3 * w3;
        float inv = 1.f / (ssum + 1e-16f);
        o.x = (a0.x*w0 + a1.x*w1 + a2.x*w2 + a3.x*w3) * inv;
        o.y = (a0.y*w0 + a1.y*w1 + a2.y*w2 + a3.y*w3) * inv;
        o.z = (a0.z*w0 + a1.z*w1 + a2.z*w2 + a3.z*w3) * inv;
        o.w = (a0.w*w0 + a1.w*w1 + a2.w*w2 + a3.w*w3) * inv;
    }
    *(float4*)(out + (size_t)n * 128 + 4 * l) = o;
}

// ---------------- pred: one block per m-node, Em row in regs, gathered Ed rows ----------------
__global__ __launch_bounds__(64) void pred_kernel(
    const float* __restrict__ Em, const float* __restrict__ Ed,
    const int* __restrict__ eidx,
    const int* __restrict__ rpm, const int* __restrict__ porder,
    float* __restrict__ out)
{
    int m = blockIdx.x;
    int lane = threadIdx.x;
    int beg = rpm[m], end = rpm[m + 1];
    if (beg == end) return;
    float4 a = *(const float4*)(Em + (size_t)m * 256 + 4 * lane);
    int i = beg;
    for (; i + 2 <= end; i += 2) {
        int p0 = porder[i], p1 = porder[i + 1];
        int d0 = eidx[Pc + p0], d1 = eidx[Pc + p1];
        float4 b0 = *(const float4*)(Ed + (size_t)d0 * 256 + 4 * lane);
        float4 b1 = *(const float4*)(Ed + (size_t)d1 * 256 + 4 * lane);
        float s0 = a.x*b0.x + a.y*b0.y + a.z*b0.z + a.w*b0.w;
        float s1 = a.x*b1.x + a.y*b1.y + a.z*b1.z + a.w*b1.w;
        #pragma unroll
        for (int o = 1; o < 64; o <<= 1) { s0 += __shfl_xor(s0, o); s1 += __shfl_xor(s1, o); }
        if (lane == 0) { out[p0] = s0; out[p1] = s1; }
    }
    if (i < end) {
        int p0 = porder[i];
        int d0 = eidx[Pc + p0];
        float4 b0 = *(const float4*)(Ed + (size_t)d0 * 256 + 4 * lane);
        float s0 = a.x*b0.x + a.y*b0.y + a.z*b0.z + a.w*b0.w;
        #pragma unroll
        for (int o = 1; o < 64; o <<= 1) s0 += __shfl_xor(s0, o);
        if (lane == 0) out[p0] = s0;
    }
}

extern "C" void kernel_launch(void* const* d_in, const int* in_sizes, int n_in,
                              void* d_out, int out_size, void* d_ws, size_t ws_size,
                              hipStream_t stream)
{
    const float* x1   = (const float*)d_in[0];
    const float* x2   = (const float*)d_in[1];
    const int*   ei12 = (const int*)d_in[2];
    const int*   ei21 = (const int*)d_in[3];
    const int*   eidx = (const int*)d_in[4];
    const float* Win1 = (const float*)d_in[5];
    const float* bin1 = (const float*)d_in[6];
    const float* Win2 = (const float*)d_in[7];
    const float* bin2 = (const float*)d_in[8];
    const float* Wk   = (const float*)d_in[9];
    const float* bk   = (const float*)d_in[10];
    const float* Wq   = (const float*)d_in[11];
    const float* bq   = (const float*)d_in[12];
    const float* Wv   = (const float*)d_in[13];
    const float* bv   = (const float*)d_in[14];
    const float* Wa   = (const float*)d_in[15];
    const float* ba   = (const float*)d_in[16];
    const float* skip = (const float*)d_in[17];
    const float* arel = (const float*)d_in[18];
    const float* mrel = (const float*)d_in[19];
    const float* prior= (const float*)d_in[20];

    char* ws = (char*)d_ws;
    size_t off = 0;
    auto allocF = [&](size_t n) { float* p = (float*)(ws + off); off += n * sizeof(float); return p; };
    auto allocI = [&](size_t n) { int* p = (int*)(ws + off); off += n * sizeof(int); return p; };
    auto allocU = [&](size_t n) { unsigned short* p = (unsigned short*)(ws + off); off += ((n * 2 + 15) & ~15ull); return p; };

    float* h1    = allocF((size_t)N1c * 128);
    float* h2    = allocF((size_t)N2c * 128);
    float* Q1    = allocF((size_t)N1c * 128);
    float* Q2    = allocF((size_t)N2c * 128);
    float* agg1  = allocF((size_t)N1c * 128);
    float* agg2  = allocF((size_t)N2c * 128);
    float* Em    = allocF((size_t)N1c * 256);
    float* Ed    = allocF((size_t)N2c * 256);
    float* Wqkv  = allocF(4 * 128 * 384);
    float* bqkv  = allocF(4 * 384);
    unsigned short* KV1 = allocU((size_t)N1c * 256);
    unsigned short* KV2 = allocU((size_t)N2c * 256);
    int* deg12 = allocI(N2c);      // contiguous zero block: deg12,deg21,degm,fill12,fill21,fillm
    int* deg21 = allocI(N1c);
    int* degm  = allocI(N1c);
    int* fill12 = allocI(N2c);
    int* fill21 = allocI(N1c);
    int* fillm  = allocI(N1c);
    int* rp12  = allocI(N2c + 1);
    int* rp21  = allocI(N1c + 1);
    int* rpm   = allocI(N1c + 1);
    int* es12  = allocI(Ec);
    int* es21  = allocI(Ec);
    int* ps    = allocI(Pc);

    hipMemsetAsync(deg12, 0, (size_t)60000 * sizeof(int), stream);

    make_eff_kernel<<<dim3(3, 128, 4), 128, 0, stream>>>(
        Wq, bq, Wk, bk, Wv, bv, arel, mrel, prior, Wqkv, bqkv);

    const int EB = (Ec + 255) / 256;
    hist3_kernel<<<dim3(EB, 3), 256, 0, stream>>>(ei12, ei21, eidx, deg12, deg21, degm);
    scan3_kernel<<<3, 1024, 0, stream>>>(deg12, rp12, deg21, rp21, degm, rpm);
    scatter3_kernel<<<dim3(EB, 3), 256, 0, stream>>>(ei12, ei21, eidx, rp12, rp21, rpm,
                                                     fill12, fill21, fillm, es12, es21, ps);

    const int MB = (N1c + 63) / 64;   // 157
    // input projections (relu), both node sets in one dispatch
    gemm2_kernel<0, 1, 0, 0><<<dim3(MB, 2, 2), 256, 0, stream>>>(
        x1, x2, F_INc, Win1, Win2, 128, bin1, bin2, h1, h2, 128,
        nullptr, nullptr,
        N1c, F_INc, nullptr, nullptr, nullptr, nullptr, 0);

    for (int l = 0; l < Lc; l++) {
        const float* A1 = (l == 0) ? h1 : Em;  int ld1 = (l == 0) ? 128 : 256;
        const float* A2 = (l == 0) ? h2 : Ed;
        int lt0 = l * 2 + 0, lt1 = l * 2 + 1;
        // fused QKV projections, Q fp32 + KV bf16 packed
        gemm2_kernel<0, 0, 0, 1><<<dim3(MB, 6, 2), 256, 0, stream>>>(
            A1, A2, ld1,
            Wqkv + (size_t)lt0 * 49152, Wqkv + (size_t)lt1 * 49152, 384,
            bqkv + lt0 * 384, bqkv + lt1 * 384,
            Q1, Q2, 128,
            KV1, KV2,
            N1c, 128,
            nullptr, nullptr, nullptr, nullptr, 0);
        // both attends in one dispatch
        attend2_kernel<<<(N1c + N2c) / 2, 64, 0, stream>>>(
            Q1, KV1, Q2, KV2, rp12, es12, rp21, es21, agg1, agg2);
        // output GEMMs (gelu on A, skip blend) into concat buffers
        gemm2_kernel<1, 0, 1, 0><<<dim3(MB, 2, 2), 256, 0, stream>>>(
            agg1, agg2, 128,
            Wa + (size_t)lt0 * 16384, Wa + (size_t)lt1 * 16384, 128,
            ba + lt0 * 128, ba + lt1 * 128,
            Em + l * 128, Ed + l * 128, 256,
            nullptr, nullptr,
            N1c, 128,
            skip + lt0, skip + lt1,
            A1, A2, ld1);
    }

    pred_kernel<<<N1c, 64, 0, stream>>>(Em, Ed, eidx, rpm, ps, (float*)d_out);
}